// Round 5
// baseline (127.884 us; speedup 1.0000x reference)
//
#include <hip/hip_runtime.h>
#include <math.h>

// Forward kinematics as an associative scan over affine pairs (M, p):
//   elem_j = (R_j, l_j * R_j[:,2]);  (M1,p1) ⊗ (M2,p2) = (M1*M2, p1 + M1*p2)
// Output_i = p-component of inclusive prefix up to i.
//
// R4: single-pass decoupled-lookback scan. Per block: local fold (trig) ->
// wave shuffle scan -> publish 48B aggregate + release flag -> wave 0
// window-folds predecessor aggregates (64-wide, ordered shfl reduce, spin on
// acquire flags) -> apply prefix -> write. All 1024 blocks co-resident
// (launch_bounds(256,4) caps VGPR at 128 => 4 waves/SIMD * 1024 SIMDs), and
// blocks wait only on lower block ids => progress guaranteed regardless of
// dispatch order. Flags zeroed via captured hipMemsetAsync.

#define TPB 256          // threads per block
#define EPT 4            // elements per thread
#define EPB (TPB * EPT)  // 1024 elements per block
#define MAXB 1024        // max blocks (N = 2^20 / 1024)
#define NWAVE (TPB / 64)

struct Xf {
    float m[9];  // row-major 3x3
    float p[3];
};

__device__ __forceinline__ void xf_identity(Xf& x) {
    x.m[0] = 1.f; x.m[1] = 0.f; x.m[2] = 0.f;
    x.m[3] = 0.f; x.m[4] = 1.f; x.m[5] = 0.f;
    x.m[6] = 0.f; x.m[7] = 0.f; x.m[8] = 1.f;
    x.p[0] = 0.f; x.p[1] = 0.f; x.p[2] = 0.f;
}

// out = A ⊗ B  (A is the earlier prefix)
__device__ __forceinline__ Xf xf_comb(const Xf& A, const Xf& B) {
    Xf o;
#pragma unroll
    for (int r = 0; r < 3; ++r) {
        const float a0 = A.m[r * 3 + 0], a1 = A.m[r * 3 + 1], a2 = A.m[r * 3 + 2];
#pragma unroll
        for (int c = 0; c < 3; ++c) {
            o.m[r * 3 + c] = a0 * B.m[0 * 3 + c] + a1 * B.m[1 * 3 + c] + a2 * B.m[2 * 3 + c];
        }
        o.p[r] = A.p[r] + a0 * B.p[0] + a1 * B.p[1] + a2 * B.p[2];
    }
    return o;
}

// a = a ⊗ elem(theta=(ax,ay,az), l).  R = Rz@Ry@Rx (ZYX Euler).
// ACCURATE sincosf (ocml ~1ulp): fast __sincosf random-walks past the 2% threshold.
__device__ __forceinline__ void xf_fold(Xf& a, float ax, float ay, float az, float l) {
    float sx, cx, sy, cy, sz, cz;
    sincosf(ax, &sx, &cx);
    sincosf(ay, &sy, &cy);
    sincosf(az, &sz, &cz);
    const float sysx = sy * sx, sycx = sy * cx;
    const float r00 = cz * cy;
    const float r01 = cz * sysx - sz * cx;
    const float r02 = sz * sx + cz * sycx;
    const float r10 = sz * cy;
    const float r11 = cz * cx + sz * sysx;
    const float r12 = sz * sycx - cz * sx;
    const float r20 = -sy;
    const float r21 = cy * sx;
    const float r22 = cy * cx;
    const float t0 = l * r02, t1 = l * r12, t2 = l * r22;
    const float p0 = a.p[0] + a.m[0] * t0 + a.m[1] * t1 + a.m[2] * t2;
    const float p1 = a.p[1] + a.m[3] * t0 + a.m[4] * t1 + a.m[5] * t2;
    const float p2 = a.p[2] + a.m[6] * t0 + a.m[7] * t1 + a.m[8] * t2;
    const float n0 = a.m[0] * r00 + a.m[1] * r10 + a.m[2] * r20;
    const float n1 = a.m[0] * r01 + a.m[1] * r11 + a.m[2] * r21;
    const float n2 = a.m[0] * r02 + a.m[1] * r12 + a.m[2] * r22;
    const float n3 = a.m[3] * r00 + a.m[4] * r10 + a.m[5] * r20;
    const float n4 = a.m[3] * r01 + a.m[4] * r11 + a.m[5] * r21;
    const float n5 = a.m[3] * r02 + a.m[4] * r12 + a.m[5] * r22;
    const float n6 = a.m[6] * r00 + a.m[7] * r10 + a.m[8] * r20;
    const float n7 = a.m[6] * r01 + a.m[7] * r11 + a.m[8] * r21;
    const float n8 = a.m[6] * r02 + a.m[7] * r12 + a.m[8] * r22;
    a.m[0] = n0; a.m[1] = n1; a.m[2] = n2;
    a.m[3] = n3; a.m[4] = n4; a.m[5] = n5;
    a.m[6] = n6; a.m[7] = n7; a.m[8] = n8;
    a.p[0] = p0; a.p[1] = p1; a.p[2] = p2;
}

// ---- wave shuffle helpers ----
__device__ __forceinline__ Xf xf_shfl_up(const Xf& a, int delta) {
    Xf o;
#pragma unroll
    for (int k = 0; k < 9; ++k) o.m[k] = __shfl_up(a.m[k], delta, 64);
#pragma unroll
    for (int k = 0; k < 3; ++k) o.p[k] = __shfl_up(a.p[k], delta, 64);
    return o;
}
__device__ __forceinline__ Xf xf_shfl_down(const Xf& a, int delta) {
    Xf o;
#pragma unroll
    for (int k = 0; k < 9; ++k) o.m[k] = __shfl_down(a.m[k], delta, 64);
#pragma unroll
    for (int k = 0; k < 3; ++k) o.p[k] = __shfl_down(a.p[k], delta, 64);
    return o;
}
__device__ __forceinline__ Xf xf_bcast0(const Xf& a) {
    Xf o;
#pragma unroll
    for (int k = 0; k < 9; ++k) o.m[k] = __shfl(a.m[k], 0, 64);
#pragma unroll
    for (int k = 0; k < 3; ++k) o.p[k] = __shfl(a.p[k], 0, 64);
    return o;
}

// Inclusive scan across the 64-lane wave (no barriers, no LDS).
__device__ __forceinline__ Xf wave_scan(Xf a, int lane) {
#pragma unroll
    for (int off = 1; off < 64; off <<= 1) {
        const Xf b = xf_shfl_up(a, off);
        if (lane >= off) a = xf_comb(b, a);
    }
    return a;
}

// ---- Xf <-> global as 3x float4 (Xf is 12 consecutive floats) ----
__device__ __forceinline__ Xf xf_load4(const Xf* p) {
    const float4* g = (const float4*)p;
    const float4 x = g[0], y = g[1], z = g[2];
    Xf b;
    b.m[0] = x.x; b.m[1] = x.y; b.m[2] = x.z;
    b.m[3] = x.w; b.m[4] = y.x; b.m[5] = y.y;
    b.m[6] = y.z; b.m[7] = y.w; b.m[8] = z.x;
    b.p[0] = z.y; b.p[1] = z.z; b.p[2] = z.w;
    return b;
}
__device__ __forceinline__ void xf_store4(Xf* p, const Xf& b) {
    float4* g = (float4*)p;
    g[0] = make_float4(b.m[0], b.m[1], b.m[2], b.m[3]);
    g[1] = make_float4(b.m[4], b.m[5], b.m[6], b.m[7]);
    g[2] = make_float4(b.m[8], b.p[0], b.p[1], b.p[2]);
}

// ---- local fold of EPT elements, recording per-element positions ----
__device__ __forceinline__ void local_fold(const float* __restrict__ ll,
                                           const float* __restrict__ th,
                                           long long j0, int n, Xf& a,
                                           float pe[EPT][3]) {
    xf_identity(a);
    if (j0 + EPT <= n) {
        const float4* th4 = (const float4*)(th + 3 * j0);
        const float4 A = th4[0], B = th4[1], C = th4[2];
        const float4 L = *(const float4*)(ll + j0);
        xf_fold(a, A.x, A.y, A.z, L.x);
        pe[0][0] = a.p[0]; pe[0][1] = a.p[1]; pe[0][2] = a.p[2];
        xf_fold(a, A.w, B.x, B.y, L.y);
        pe[1][0] = a.p[0]; pe[1][1] = a.p[1]; pe[1][2] = a.p[2];
        xf_fold(a, B.z, B.w, C.x, L.z);
        pe[2][0] = a.p[0]; pe[2][1] = a.p[1]; pe[2][2] = a.p[2];
        xf_fold(a, C.y, C.z, C.w, L.w);
        pe[3][0] = a.p[0]; pe[3][1] = a.p[1]; pe[3][2] = a.p[2];
    } else {
#pragma unroll
        for (int e = 0; e < EPT; ++e) {
            const long long j = j0 + e;
            if (j < n) xf_fold(a, th[3 * j + 0], th[3 * j + 1], th[3 * j + 2], ll[j]);
            pe[e][0] = a.p[0]; pe[e][1] = a.p[1]; pe[e][2] = a.p[2];
        }
    }
}

__device__ __forceinline__ void write_out(float* __restrict__ out, long long j0, int n,
                                          const Xf& T, const float pe[EPT][3]) {
    if (j0 + EPT <= n) {
        float o[EPT * 3];
#pragma unroll
        for (int e = 0; e < EPT; ++e) {
            const float q0 = pe[e][0], q1 = pe[e][1], q2 = pe[e][2];
            o[e * 3 + 0] = T.p[0] + T.m[0] * q0 + T.m[1] * q1 + T.m[2] * q2;
            o[e * 3 + 1] = T.p[1] + T.m[3] * q0 + T.m[4] * q1 + T.m[5] * q2;
            o[e * 3 + 2] = T.p[2] + T.m[6] * q0 + T.m[7] * q1 + T.m[8] * q2;
        }
        float4* o4 = (float4*)(out + 3 * j0);
        o4[0] = make_float4(o[0], o[1], o[2], o[3]);
        o4[1] = make_float4(o[4], o[5], o[6], o[7]);
        o4[2] = make_float4(o[8], o[9], o[10], o[11]);
    } else {
#pragma unroll
        for (int e = 0; e < EPT; ++e) {
            const long long j = j0 + e;
            if (j < n) {
                const float q0 = pe[e][0], q1 = pe[e][1], q2 = pe[e][2];
                out[3 * j + 0] = T.p[0] + T.m[0] * q0 + T.m[1] * q1 + T.m[2] * q2;
                out[3 * j + 1] = T.p[1] + T.m[3] * q0 + T.m[4] * q1 + T.m[5] * q2;
                out[3 * j + 2] = T.p[2] + T.m[6] * q0 + T.m[7] * q1 + T.m[8] * q2;
            }
        }
    }
}

// ================= single-pass decoupled-lookback kernel =================
__global__ void __launch_bounds__(TPB, 4)
fk_lookback(const float* __restrict__ ll, const float* __restrict__ th,
            Xf* __restrict__ agg, unsigned* __restrict__ flags,
            float* __restrict__ out, int n) {
    __shared__ Xf wagg[NWAVE];
    __shared__ Xf shG;
    const int t = threadIdx.x, bid = blockIdx.x;
    const int lane = t & 63, w = t >> 6;
    const long long j0 = (long long)bid * EPB + (long long)t * EPT;

    // 1. local fold + wave scan
    Xf a;
    float pe[EPT][3];
    local_fold(ll, th, j0, n, a, pe);
    const Xf inc = wave_scan(a, lane);
    if (lane == 63) wagg[w] = inc;
    __syncthreads();

    // 2. publish block aggregate (last thread) — runs while wave 0 looks back
    if (t == TPB - 1) {
        Xf acc = wagg[0];
#pragma unroll
        for (int k = 1; k < NWAVE - 1; ++k) acc = xf_comb(acc, wagg[k]);
        acc = xf_comb(acc, inc);
        xf_store4(&agg[bid], acc);
        __threadfence();  // make payload visible device-wide before flag
        __hip_atomic_store(&flags[bid], 1u, __ATOMIC_RELEASE, __HIP_MEMORY_SCOPE_AGENT);
    }

    // 3. wave 0: window-fold predecessors' aggregates -> G = agg[0..bid)
    if (w == 0) {
        Xf G;
        xf_identity(G);
        const int fullw = bid >> 6, rem = bid & 63;
        for (int win = 0; win < fullw; ++win) {
            const int idx = (win << 6) + lane;
            while (__hip_atomic_load(&flags[idx], __ATOMIC_ACQUIRE,
                                     __HIP_MEMORY_SCOPE_AGENT) == 0u) {
                __builtin_amdgcn_s_sleep(1);
            }
            Xf v = xf_load4(&agg[idx]);
#pragma unroll
            for (int off = 1; off < 64; off <<= 1) {
                const Xf b = xf_shfl_down(v, off);
                if (lane + off < 64) v = xf_comb(v, b);
            }
            G = xf_comb(G, xf_bcast0(v));  // ordered: windows low -> high
        }
        if (rem) {
            const int idx = (fullw << 6) + lane;
            Xf v;
            if (lane < rem) {
                while (__hip_atomic_load(&flags[idx], __ATOMIC_ACQUIRE,
                                         __HIP_MEMORY_SCOPE_AGENT) == 0u) {
                    __builtin_amdgcn_s_sleep(1);
                }
                v = xf_load4(&agg[idx]);
            } else {
                xf_identity(v);
            }
#pragma unroll
            for (int off = 1; off < 64; off <<= 1) {
                const Xf b = xf_shfl_down(v, off);
                if (lane + off < 64) v = xf_comb(v, b);
            }
            G = xf_comb(G, xf_bcast0(v));
        }
        if (lane == 0) shG = G;
    }
    __syncthreads();

    // 4. apply prefixes and write out
    Xf exw;  // cross-wave exclusive prefix within block (broadcast LDS reads)
    xf_identity(exw);
    for (int k = 0; k < w; ++k) exw = xf_comb(exw, wagg[k]);

    const Xf ext = xf_shfl_up(inc, 1);  // thread-exclusive within wave

    Xf T = xf_comb(shG, exw);
    if (lane != 0) T = xf_comb(T, ext);

    write_out(out, j0, n, T, pe);
}

extern "C" void kernel_launch(void* const* d_in, const int* in_sizes, int n_in,
                              void* d_out, int out_size, void* d_ws, size_t ws_size,
                              hipStream_t stream) {
    const float* ll = (const float*)d_in[0];   // link_lengths [N]
    const float* th = (const float*)d_in[1];   // theta [N,3]
    float* out = (float*)d_out;                // [N,3] f32
    const int n = in_sizes[0];

    int nb = (n + EPB - 1) / EPB;              // 1024 for N = 2^20
    if (nb > MAXB) nb = MAXB;

    Xf* agg = (Xf*)d_ws;                       // 48 KB
    unsigned* flags = (unsigned*)((char*)d_ws + MAXB * sizeof(Xf));  // 4 KB

    // zero the ready-flags each launch (captured in the graph, replayed)
    hipMemsetAsync(flags, 0, nb * sizeof(unsigned), stream);
    fk_lookback<<<nb, TPB, 0, stream>>>(ll, th, agg, flags, out, n);
}

// Round 6
// 30.825 us; speedup vs baseline: 4.1487x; 4.1487x over previous
//
#include <hip/hip_runtime.h>
#include <math.h>

// Forward kinematics as an associative scan over affine pairs (M, p):
//   elem_j = (R_j, l_j * R_j[:,2]);  (M1,p1) ⊗ (M2,p2) = (M1*M2, p1 + M1*p2)
// Output_i = p-component of inclusive prefix up to i.
//
// R5: two-kernel scan. K1: per-block aggregates (fold + wave shuffle scan).
// K2: per-block REDUNDANT ordered reduce of preceding aggregates (thread
// serial-fold 4 + ordered shfl_down wave reduce + cross-wave combine) -> G,
// then fold + wave scan + apply + write. No atomics, no spin (R4's lookback
// cost ~110us in agent-scope flag traffic on 8 non-coherent XCDs).

#define TPB 256          // threads per block
#define EPT 4            // elements per thread
#define EPB (TPB * EPT)  // 1024 elements per block
#define MAXB 1024        // max blocks (N = 2^20 / 1024)
#define NWAVE (TPB / 64)

struct Xf {
    float m[9];  // row-major 3x3
    float p[3];
};

__device__ __forceinline__ void xf_identity(Xf& x) {
    x.m[0] = 1.f; x.m[1] = 0.f; x.m[2] = 0.f;
    x.m[3] = 0.f; x.m[4] = 1.f; x.m[5] = 0.f;
    x.m[6] = 0.f; x.m[7] = 0.f; x.m[8] = 1.f;
    x.p[0] = 0.f; x.p[1] = 0.f; x.p[2] = 0.f;
}

// out = A ⊗ B  (A is the earlier prefix)
__device__ __forceinline__ Xf xf_comb(const Xf& A, const Xf& B) {
    Xf o;
#pragma unroll
    for (int r = 0; r < 3; ++r) {
        const float a0 = A.m[r * 3 + 0], a1 = A.m[r * 3 + 1], a2 = A.m[r * 3 + 2];
#pragma unroll
        for (int c = 0; c < 3; ++c) {
            o.m[r * 3 + c] = a0 * B.m[0 * 3 + c] + a1 * B.m[1 * 3 + c] + a2 * B.m[2 * 3 + c];
        }
        o.p[r] = A.p[r] + a0 * B.p[0] + a1 * B.p[1] + a2 * B.p[2];
    }
    return o;
}

// a = a ⊗ elem(theta=(ax,ay,az), l).  R = Rz@Ry@Rx (ZYX Euler).
// ACCURATE sincosf (ocml ~1ulp): fast __sincosf random-walks past the 2% threshold.
__device__ __forceinline__ void xf_fold(Xf& a, float ax, float ay, float az, float l) {
    float sx, cx, sy, cy, sz, cz;
    sincosf(ax, &sx, &cx);
    sincosf(ay, &sy, &cy);
    sincosf(az, &sz, &cz);
    const float sysx = sy * sx, sycx = sy * cx;
    const float r00 = cz * cy;
    const float r01 = cz * sysx - sz * cx;
    const float r02 = sz * sx + cz * sycx;
    const float r10 = sz * cy;
    const float r11 = cz * cx + sz * sysx;
    const float r12 = sz * sycx - cz * sx;
    const float r20 = -sy;
    const float r21 = cy * sx;
    const float r22 = cy * cx;
    const float t0 = l * r02, t1 = l * r12, t2 = l * r22;
    const float p0 = a.p[0] + a.m[0] * t0 + a.m[1] * t1 + a.m[2] * t2;
    const float p1 = a.p[1] + a.m[3] * t0 + a.m[4] * t1 + a.m[5] * t2;
    const float p2 = a.p[2] + a.m[6] * t0 + a.m[7] * t1 + a.m[8] * t2;
    const float n0 = a.m[0] * r00 + a.m[1] * r10 + a.m[2] * r20;
    const float n1 = a.m[0] * r01 + a.m[1] * r11 + a.m[2] * r21;
    const float n2 = a.m[0] * r02 + a.m[1] * r12 + a.m[2] * r22;
    const float n3 = a.m[3] * r00 + a.m[4] * r10 + a.m[5] * r20;
    const float n4 = a.m[3] * r01 + a.m[4] * r11 + a.m[5] * r21;
    const float n5 = a.m[3] * r02 + a.m[4] * r12 + a.m[5] * r22;
    const float n6 = a.m[6] * r00 + a.m[7] * r10 + a.m[8] * r20;
    const float n7 = a.m[6] * r01 + a.m[7] * r11 + a.m[8] * r21;
    const float n8 = a.m[6] * r02 + a.m[7] * r12 + a.m[8] * r22;
    a.m[0] = n0; a.m[1] = n1; a.m[2] = n2;
    a.m[3] = n3; a.m[4] = n4; a.m[5] = n5;
    a.m[6] = n6; a.m[7] = n7; a.m[8] = n8;
    a.p[0] = p0; a.p[1] = p1; a.p[2] = p2;
}

// ---- wave shuffle helpers ----
__device__ __forceinline__ Xf xf_shfl_up(const Xf& a, int delta) {
    Xf o;
#pragma unroll
    for (int k = 0; k < 9; ++k) o.m[k] = __shfl_up(a.m[k], delta, 64);
#pragma unroll
    for (int k = 0; k < 3; ++k) o.p[k] = __shfl_up(a.p[k], delta, 64);
    return o;
}
__device__ __forceinline__ Xf xf_shfl_down(const Xf& a, int delta) {
    Xf o;
#pragma unroll
    for (int k = 0; k < 9; ++k) o.m[k] = __shfl_down(a.m[k], delta, 64);
#pragma unroll
    for (int k = 0; k < 3; ++k) o.p[k] = __shfl_down(a.p[k], delta, 64);
    return o;
}

// Inclusive scan across the 64-lane wave (no barriers, no LDS).
__device__ __forceinline__ Xf wave_scan(Xf a, int lane) {
#pragma unroll
    for (int off = 1; off < 64; off <<= 1) {
        const Xf b = xf_shfl_up(a, off);
        if (lane >= off) a = xf_comb(b, a);
    }
    return a;
}

// Ordered wave reduce: lane 0 ends with v_0 ⊗ v_1 ⊗ ... ⊗ v_63.
__device__ __forceinline__ Xf wave_reduce(Xf v, int lane) {
#pragma unroll
    for (int off = 1; off < 64; off <<= 1) {
        const Xf b = xf_shfl_down(v, off);
        if (lane + off < 64) v = xf_comb(v, b);
    }
    return v;
}

// ---- Xf <-> global as 3x float4 (Xf is 12 consecutive floats) ----
__device__ __forceinline__ Xf xf_load4(const Xf* p) {
    const float4* g = (const float4*)p;
    const float4 x = g[0], y = g[1], z = g[2];
    Xf b;
    b.m[0] = x.x; b.m[1] = x.y; b.m[2] = x.z;
    b.m[3] = x.w; b.m[4] = y.x; b.m[5] = y.y;
    b.m[6] = y.z; b.m[7] = y.w; b.m[8] = z.x;
    b.p[0] = z.y; b.p[1] = z.z; b.p[2] = z.w;
    return b;
}
__device__ __forceinline__ void xf_store4(Xf* p, const Xf& b) {
    float4* g = (float4*)p;
    g[0] = make_float4(b.m[0], b.m[1], b.m[2], b.m[3]);
    g[1] = make_float4(b.m[4], b.m[5], b.m[6], b.m[7]);
    g[2] = make_float4(b.m[8], b.p[0], b.p[1], b.p[2]);
}

// ---- local fold of EPT elements, recording per-element positions ----
__device__ __forceinline__ void local_fold(const float* __restrict__ ll,
                                           const float* __restrict__ th,
                                           long long j0, int n, Xf& a,
                                           float pe[EPT][3]) {
    xf_identity(a);
    if (j0 + EPT <= n) {
        const float4* th4 = (const float4*)(th + 3 * j0);
        const float4 A = th4[0], B = th4[1], C = th4[2];
        const float4 L = *(const float4*)(ll + j0);
        xf_fold(a, A.x, A.y, A.z, L.x);
        pe[0][0] = a.p[0]; pe[0][1] = a.p[1]; pe[0][2] = a.p[2];
        xf_fold(a, A.w, B.x, B.y, L.y);
        pe[1][0] = a.p[0]; pe[1][1] = a.p[1]; pe[1][2] = a.p[2];
        xf_fold(a, B.z, B.w, C.x, L.z);
        pe[2][0] = a.p[0]; pe[2][1] = a.p[1]; pe[2][2] = a.p[2];
        xf_fold(a, C.y, C.z, C.w, L.w);
        pe[3][0] = a.p[0]; pe[3][1] = a.p[1]; pe[3][2] = a.p[2];
    } else {
#pragma unroll
        for (int e = 0; e < EPT; ++e) {
            const long long j = j0 + e;
            if (j < n) xf_fold(a, th[3 * j + 0], th[3 * j + 1], th[3 * j + 2], ll[j]);
            pe[e][0] = a.p[0]; pe[e][1] = a.p[1]; pe[e][2] = a.p[2];
        }
    }
}

__device__ __forceinline__ void write_out(float* __restrict__ out, long long j0, int n,
                                          const Xf& T, const float pe[EPT][3]) {
    if (j0 + EPT <= n) {
        float o[EPT * 3];
#pragma unroll
        for (int e = 0; e < EPT; ++e) {
            const float q0 = pe[e][0], q1 = pe[e][1], q2 = pe[e][2];
            o[e * 3 + 0] = T.p[0] + T.m[0] * q0 + T.m[1] * q1 + T.m[2] * q2;
            o[e * 3 + 1] = T.p[1] + T.m[3] * q0 + T.m[4] * q1 + T.m[5] * q2;
            o[e * 3 + 2] = T.p[2] + T.m[6] * q0 + T.m[7] * q1 + T.m[8] * q2;
        }
        float4* o4 = (float4*)(out + 3 * j0);
        o4[0] = make_float4(o[0], o[1], o[2], o[3]);
        o4[1] = make_float4(o[4], o[5], o[6], o[7]);
        o4[2] = make_float4(o[8], o[9], o[10], o[11]);
    } else {
#pragma unroll
        for (int e = 0; e < EPT; ++e) {
            const long long j = j0 + e;
            if (j < n) {
                const float q0 = pe[e][0], q1 = pe[e][1], q2 = pe[e][2];
                out[3 * j + 0] = T.p[0] + T.m[0] * q0 + T.m[1] * q1 + T.m[2] * q2;
                out[3 * j + 1] = T.p[1] + T.m[3] * q0 + T.m[4] * q1 + T.m[5] * q2;
                out[3 * j + 2] = T.p[2] + T.m[6] * q0 + T.m[7] * q1 + T.m[8] * q2;
            }
        }
    }
}

// ---------------- K1: per-block aggregates ----------------
__global__ void __launch_bounds__(TPB) fk_agg(const float* __restrict__ ll,
                                              const float* __restrict__ th,
                                              Xf* __restrict__ agg, int n) {
    __shared__ Xf wagg[NWAVE];
    const int t = threadIdx.x;
    const int lane = t & 63, w = t >> 6;
    const long long j0 = (long long)blockIdx.x * EPB + (long long)t * EPT;

    Xf a;
    float pe[EPT][3];  // unused here (DCE'd)
    local_fold(ll, th, j0, n, a, pe);

    const Xf red = wave_reduce(a, lane);   // lane 0: wave's ordered product
    if (lane == 0) wagg[w] = red;
    __syncthreads();

    if (t == 0) {
        Xf acc = wagg[0];
#pragma unroll
        for (int k = 1; k < NWAVE; ++k) acc = xf_comb(acc, wagg[k]);
        xf_store4(&agg[blockIdx.x], acc);
    }
}

// ---------------- K2: redundant G-reduce + fold + scan + apply ----------------
__global__ void __launch_bounds__(TPB) fk_apply(const float* __restrict__ ll,
                                                const float* __restrict__ th,
                                                const Xf* __restrict__ agg,
                                                float* __restrict__ out, int n) {
    __shared__ Xf wred[NWAVE];
    __shared__ Xf wagg[NWAVE];
    __shared__ Xf shG;
    const int t = threadIdx.x, bid = blockIdx.x;
    const int lane = t & 63, w = t >> 6;
    const long long j0 = (long long)bid * EPB + (long long)t * EPT;

    // --- 1. G = agg[0] ⊗ ... ⊗ agg[bid-1], cooperatively, ordered ---
    {
        const int i0 = t * EPT;  // thread's 4-aggregate chunk
        Xf A;
        xf_identity(A);
#pragma unroll
        for (int e = 0; e < EPT; ++e) {
            const int i = i0 + e;
            if (i < bid) A = xf_comb(A, xf_load4(&agg[i]));
        }
        const Xf red = wave_reduce(A, lane);  // lane 0: wave's ordered product
        if (lane == 0) wred[w] = red;
    }
    __syncthreads();
    if (t == 0) {
        Xf G = wred[0];
#pragma unroll
        for (int k = 1; k < NWAVE; ++k) G = xf_comb(G, wred[k]);
        shG = G;
    }
    // (shG read is protected by the __syncthreads() below)

    // --- 2. local fold + wave scan (as R3 phase 3) ---
    Xf a;
    float pe[EPT][3];
    local_fold(ll, th, j0, n, a, pe);

    const Xf inc = wave_scan(a, lane);
    if (lane == 63) wagg[w] = inc;
    __syncthreads();

    Xf exw;  // cross-wave exclusive prefix (broadcast LDS reads, conflict-free)
    xf_identity(exw);
    for (int k = 0; k < w; ++k) exw = xf_comb(exw, wagg[k]);

    const Xf ext = xf_shfl_up(inc, 1);  // thread-exclusive within wave

    Xf T = xf_comb(shG, exw);
    if (lane != 0) T = xf_comb(T, ext);

    write_out(out, j0, n, T, pe);
}

extern "C" void kernel_launch(void* const* d_in, const int* in_sizes, int n_in,
                              void* d_out, int out_size, void* d_ws, size_t ws_size,
                              hipStream_t stream) {
    const float* ll = (const float*)d_in[0];   // link_lengths [N]
    const float* th = (const float*)d_in[1];   // theta [N,3]
    float* out = (float*)d_out;                // [N,3] f32
    const int n = in_sizes[0];

    int nb = (n + EPB - 1) / EPB;              // 1024 for N = 2^20
    if (nb > MAXB) nb = MAXB;

    Xf* agg = (Xf*)d_ws;                       // 48 KB

    fk_agg<<<nb, TPB, 0, stream>>>(ll, th, agg, n);
    fk_apply<<<nb, TPB, 0, stream>>>(ll, th, agg, out, n);
}

// Round 7
// 29.799 us; speedup vs baseline: 4.2916x; 1.0344x over previous
//
#include <hip/hip_runtime.h>
#include <math.h>

// Forward kinematics as an associative scan over affine pairs (M, p):
//   elem_j = (R_j, l_j * R_j[:,2]);  (M1,p1) ⊗ (M2,p2) = (M1*M2, p1 + M1*p2)
// Output_i = p-component of inclusive prefix up to i.
//
// R6: fold+scan done ONCE. K1 (512 thr, EPT=2 -> 8 waves/SIMD): local fold +
// wave shuffle scan + block scan, writes block-LOCAL inclusive positions q_j
// into out, plus 48B block aggregate. K2 (256 thr, streaming): per-block
// redundant ordered reduce of preceding aggregates -> G, then in-place fixup
// out_j = G.p + G.m @ q_j. No atomics, no spin, no duplicated trig/scan.

#define K1_TPB 512
#define K1_EPT 2
#define K1_EPB (K1_TPB * K1_EPT)   // 1024 elements per block
#define K1_NW (K1_TPB / 64)        // 8 waves
#define K2_TPB 256
#define K2_EPT 4
#define K2_EPB (K2_TPB * K2_EPT)   // 1024 elements per block (same tiling as K1)
#define MAXB 1024                  // blocks for N = 2^20
#define EPG (MAXB / K2_TPB)        // aggregates per thread in G-reduce

struct Xf {
    float m[9];  // row-major 3x3
    float p[3];
};

__device__ __forceinline__ void xf_identity(Xf& x) {
    x.m[0] = 1.f; x.m[1] = 0.f; x.m[2] = 0.f;
    x.m[3] = 0.f; x.m[4] = 1.f; x.m[5] = 0.f;
    x.m[6] = 0.f; x.m[7] = 0.f; x.m[8] = 1.f;
    x.p[0] = 0.f; x.p[1] = 0.f; x.p[2] = 0.f;
}

// out = A ⊗ B  (A is the earlier prefix)
__device__ __forceinline__ Xf xf_comb(const Xf& A, const Xf& B) {
    Xf o;
#pragma unroll
    for (int r = 0; r < 3; ++r) {
        const float a0 = A.m[r * 3 + 0], a1 = A.m[r * 3 + 1], a2 = A.m[r * 3 + 2];
#pragma unroll
        for (int c = 0; c < 3; ++c) {
            o.m[r * 3 + c] = a0 * B.m[0 * 3 + c] + a1 * B.m[1 * 3 + c] + a2 * B.m[2 * 3 + c];
        }
        o.p[r] = A.p[r] + a0 * B.p[0] + a1 * B.p[1] + a2 * B.p[2];
    }
    return o;
}

// a = a ⊗ elem(theta=(ax,ay,az), l).  R = Rz@Ry@Rx (ZYX Euler).
// ACCURATE sincosf (ocml ~1ulp): fast __sincosf random-walks past the 2% threshold.
__device__ __forceinline__ void xf_fold(Xf& a, float ax, float ay, float az, float l) {
    float sx, cx, sy, cy, sz, cz;
    sincosf(ax, &sx, &cx);
    sincosf(ay, &sy, &cy);
    sincosf(az, &sz, &cz);
    const float sysx = sy * sx, sycx = sy * cx;
    const float r00 = cz * cy;
    const float r01 = cz * sysx - sz * cx;
    const float r02 = sz * sx + cz * sycx;
    const float r10 = sz * cy;
    const float r11 = cz * cx + sz * sysx;
    const float r12 = sz * sycx - cz * sx;
    const float r20 = -sy;
    const float r21 = cy * sx;
    const float r22 = cy * cx;
    const float t0 = l * r02, t1 = l * r12, t2 = l * r22;
    const float p0 = a.p[0] + a.m[0] * t0 + a.m[1] * t1 + a.m[2] * t2;
    const float p1 = a.p[1] + a.m[3] * t0 + a.m[4] * t1 + a.m[5] * t2;
    const float p2 = a.p[2] + a.m[6] * t0 + a.m[7] * t1 + a.m[8] * t2;
    const float n0 = a.m[0] * r00 + a.m[1] * r10 + a.m[2] * r20;
    const float n1 = a.m[0] * r01 + a.m[1] * r11 + a.m[2] * r21;
    const float n2 = a.m[0] * r02 + a.m[1] * r12 + a.m[2] * r22;
    const float n3 = a.m[3] * r00 + a.m[4] * r10 + a.m[5] * r20;
    const float n4 = a.m[3] * r01 + a.m[4] * r11 + a.m[5] * r21;
    const float n5 = a.m[3] * r02 + a.m[4] * r12 + a.m[5] * r22;
    const float n6 = a.m[6] * r00 + a.m[7] * r10 + a.m[8] * r20;
    const float n7 = a.m[6] * r01 + a.m[7] * r11 + a.m[8] * r21;
    const float n8 = a.m[6] * r02 + a.m[7] * r12 + a.m[8] * r22;
    a.m[0] = n0; a.m[1] = n1; a.m[2] = n2;
    a.m[3] = n3; a.m[4] = n4; a.m[5] = n5;
    a.m[6] = n6; a.m[7] = n7; a.m[8] = n8;
    a.p[0] = p0; a.p[1] = p1; a.p[2] = p2;
}

// ---- wave shuffle helpers ----
__device__ __forceinline__ Xf xf_shfl_up(const Xf& a, int delta) {
    Xf o;
#pragma unroll
    for (int k = 0; k < 9; ++k) o.m[k] = __shfl_up(a.m[k], delta, 64);
#pragma unroll
    for (int k = 0; k < 3; ++k) o.p[k] = __shfl_up(a.p[k], delta, 64);
    return o;
}
__device__ __forceinline__ Xf xf_shfl_down(const Xf& a, int delta) {
    Xf o;
#pragma unroll
    for (int k = 0; k < 9; ++k) o.m[k] = __shfl_down(a.m[k], delta, 64);
#pragma unroll
    for (int k = 0; k < 3; ++k) o.p[k] = __shfl_down(a.p[k], delta, 64);
    return o;
}

// Inclusive scan across the 64-lane wave (no barriers, no LDS).
__device__ __forceinline__ Xf wave_scan(Xf a, int lane) {
#pragma unroll
    for (int off = 1; off < 64; off <<= 1) {
        const Xf b = xf_shfl_up(a, off);
        if (lane >= off) a = xf_comb(b, a);
    }
    return a;
}

// Ordered wave reduce: lane 0 ends with v_0 ⊗ v_1 ⊗ ... ⊗ v_63.
__device__ __forceinline__ Xf wave_reduce(Xf v, int lane) {
#pragma unroll
    for (int off = 1; off < 64; off <<= 1) {
        const Xf b = xf_shfl_down(v, off);
        if (lane + off < 64) v = xf_comb(v, b);
    }
    return v;
}

// ---- Xf <-> global as 3x float4 ----
__device__ __forceinline__ Xf xf_load4(const Xf* p) {
    const float4* g = (const float4*)p;
    const float4 x = g[0], y = g[1], z = g[2];
    Xf b;
    b.m[0] = x.x; b.m[1] = x.y; b.m[2] = x.z;
    b.m[3] = x.w; b.m[4] = y.x; b.m[5] = y.y;
    b.m[6] = y.z; b.m[7] = y.w; b.m[8] = z.x;
    b.p[0] = z.y; b.p[1] = z.z; b.p[2] = z.w;
    return b;
}
__device__ __forceinline__ void xf_store4(Xf* p, const Xf& b) {
    float4* g = (float4*)p;
    g[0] = make_float4(b.m[0], b.m[1], b.m[2], b.m[3]);
    g[1] = make_float4(b.m[4], b.m[5], b.m[6], b.m[7]);
    g[2] = make_float4(b.m[8], b.p[0], b.p[1], b.p[2]);
}

// apply affine T to point q
__device__ __forceinline__ void xf_apply(const Xf& T, float q0, float q1, float q2,
                                         float& o0, float& o1, float& o2) {
    o0 = T.p[0] + T.m[0] * q0 + T.m[1] * q1 + T.m[2] * q2;
    o1 = T.p[1] + T.m[3] * q0 + T.m[4] * q1 + T.m[5] * q2;
    o2 = T.p[2] + T.m[6] * q0 + T.m[7] * q1 + T.m[8] * q2;
}

// ================= K1: fold + block scan, write block-local q =================
__global__ void __launch_bounds__(K1_TPB, 6)
fk_local(const float* __restrict__ ll, const float* __restrict__ th,
         Xf* __restrict__ agg, float* __restrict__ out, int n) {
    __shared__ Xf wagg[K1_NW];
    const int t = threadIdx.x, bid = blockIdx.x;
    const int lane = t & 63, w = t >> 6;
    const long long j0 = (long long)bid * K1_EPB + (long long)t * K1_EPT;

    // local fold of 2 elements, recording per-element positions
    Xf a;
    xf_identity(a);
    float pe[K1_EPT][3];
    if (j0 + K1_EPT <= n) {
        const float2* th2 = (const float2*)(th + 3 * j0);  // 24B-aligned
        const float2 d0 = th2[0], d1 = th2[1], d2 = th2[2];
        const float2 L = *(const float2*)(ll + j0);
        xf_fold(a, d0.x, d0.y, d1.x, L.x);
        pe[0][0] = a.p[0]; pe[0][1] = a.p[1]; pe[0][2] = a.p[2];
        xf_fold(a, d1.y, d2.x, d2.y, L.y);
        pe[1][0] = a.p[0]; pe[1][1] = a.p[1]; pe[1][2] = a.p[2];
    } else {
#pragma unroll
        for (int e = 0; e < K1_EPT; ++e) {
            const long long j = j0 + e;
            if (j < n) xf_fold(a, th[3 * j + 0], th[3 * j + 1], th[3 * j + 2], ll[j]);
            pe[e][0] = a.p[0]; pe[e][1] = a.p[1]; pe[e][2] = a.p[2];
        }
    }

    const Xf inc = wave_scan(a, lane);
    if (lane == 63) wagg[w] = inc;
    __syncthreads();

    Xf exw;  // cross-wave exclusive prefix (broadcast LDS reads, conflict-free)
    xf_identity(exw);
    for (int k = 0; k < w; ++k) exw = xf_comb(exw, wagg[k]);

    // last thread publishes block aggregate
    if (t == K1_TPB - 1) xf_store4(&agg[bid], xf_comb(exw, inc));

    const Xf ext = xf_shfl_up(inc, 1);  // thread-exclusive within wave
    Xf T = exw;
    if (lane != 0) T = xf_comb(T, ext);

    // q_j = block-local inclusive position -> out (fixed up by K2)
    if (j0 + K1_EPT <= n) {
        float o0, o1, o2, o3, o4, o5;
        xf_apply(T, pe[0][0], pe[0][1], pe[0][2], o0, o1, o2);
        xf_apply(T, pe[1][0], pe[1][1], pe[1][2], o3, o4, o5);
        float2* q2 = (float2*)(out + 3 * j0);  // 24B-aligned
        q2[0] = make_float2(o0, o1);
        q2[1] = make_float2(o2, o3);
        q2[2] = make_float2(o4, o5);
    } else {
#pragma unroll
        for (int e = 0; e < K1_EPT; ++e) {
            const long long j = j0 + e;
            if (j < n) {
                float o0, o1, o2;
                xf_apply(T, pe[e][0], pe[e][1], pe[e][2], o0, o1, o2);
                out[3 * j + 0] = o0; out[3 * j + 1] = o1; out[3 * j + 2] = o2;
            }
        }
    }
}

// ================= K2: redundant G-reduce + in-place fixup =================
__global__ void __launch_bounds__(K2_TPB)
fk_fixup(const Xf* __restrict__ agg, float* __restrict__ out, int n, int nb) {
    __shared__ Xf wred[K2_TPB / 64];
    __shared__ Xf shG;
    const int t = threadIdx.x, bid = blockIdx.x;
    const int lane = t & 63, w = t >> 6;

    // G = agg[0] ⊗ ... ⊗ agg[bid-1], cooperatively, ordered
    {
        const int i0 = t * EPG;
        Xf A;
        xf_identity(A);
#pragma unroll
        for (int e = 0; e < EPG; ++e) {
            const int i = i0 + e;
            if (i < bid) A = xf_comb(A, xf_load4(&agg[i]));
        }
        const Xf red = wave_reduce(A, lane);
        if (lane == 0) wred[w] = red;
    }
    __syncthreads();
    if (t == 0) {
        Xf G = wred[0];
#pragma unroll
        for (int k = 1; k < K2_TPB / 64; ++k) G = xf_comb(G, wred[k]);
        shG = G;
    }
    __syncthreads();
    const Xf G = shG;

    // in-place affine fixup: out_j = G.p + G.m @ q_j
    const long long j0 = (long long)bid * K2_EPB + (long long)t * K2_EPT;
    if (j0 + K2_EPT <= n) {
        float4* o4 = (float4*)(out + 3 * j0);  // 48B-aligned
        const float4 x = o4[0], y = o4[1], z = o4[2];
        float r[12];
        xf_apply(G, x.x, x.y, x.z, r[0], r[1], r[2]);
        xf_apply(G, x.w, y.x, y.y, r[3], r[4], r[5]);
        xf_apply(G, y.z, y.w, z.x, r[6], r[7], r[8]);
        xf_apply(G, z.y, z.z, z.w, r[9], r[10], r[11]);
        o4[0] = make_float4(r[0], r[1], r[2], r[3]);
        o4[1] = make_float4(r[4], r[5], r[6], r[7]);
        o4[2] = make_float4(r[8], r[9], r[10], r[11]);
    } else {
#pragma unroll
        for (int e = 0; e < K2_EPT; ++e) {
            const long long j = j0 + e;
            if (j < n) {
                float o0, o1, o2;
                xf_apply(G, out[3 * j + 0], out[3 * j + 1], out[3 * j + 2], o0, o1, o2);
                out[3 * j + 0] = o0; out[3 * j + 1] = o1; out[3 * j + 2] = o2;
            }
        }
    }
}

extern "C" void kernel_launch(void* const* d_in, const int* in_sizes, int n_in,
                              void* d_out, int out_size, void* d_ws, size_t ws_size,
                              hipStream_t stream) {
    const float* ll = (const float*)d_in[0];   // link_lengths [N]
    const float* th = (const float*)d_in[1];   // theta [N,3]
    float* out = (float*)d_out;                // [N,3] f32
    const int n = in_sizes[0];

    int nb = (n + K1_EPB - 1) / K1_EPB;        // 1024 for N = 2^20
    if (nb > MAXB) nb = MAXB;

    Xf* agg = (Xf*)d_ws;                       // 48 KB

    fk_local<<<nb, K1_TPB, 0, stream>>>(ll, th, agg, out, n);
    fk_fixup<<<nb, K2_TPB, 0, stream>>>(agg, out, n, nb);
}